// Round 1
// baseline (377.298 us; speedup 1.0000x reference)
//
#include <hip/hip_runtime.h>
#include <math.h>

// Problem constants (from reference): B=4,S=4096,IN=2048,E=16,D=128,A=128,R=4
#define NTOK   16384   // B*S
#define INDIM  2048
#define NEXP   16
#define DDIM   128
#define NROWS  20      // 16 Wv rows + 4 mlp_w1 rows

// workspace (float) layout
#define WS_PKT  0      // PKt[e2][r][e]  : 16*4*16 = 1024
#define WS_D1K  1024   // [e2][e] 256
#define WS_GQK  1280   // [e2][e] 256
#define WS_BQK  1536   // [e2][e] 256
#define WS_SCAL 1792   // m0,q0,mW[4],q1[4],Q2[16] = 26
#define WS_TOT  1818

#define SIM_SCALE 0.08838834764831845f  // 1/sqrt(128)

// ---------------------------------------------------------------------------
// Precompute kernel: single block, 1024 threads.
// ge = LN2(expert_embedding); K[e2,a] = ge[e2,:]·Wk[a,:];
// WqK[e2,d] = sum_a Wq[a,d]*K[e2,a];
// PKt[e2,r,e] = sum_d w2[e,d,r]*gamma[e,d]*WqK[e2,d]
// D1K = sum_d b2*gamma*WqK ; GqK = sum_d gamma*WqK ; BqK = sum_d beta*WqK
// scalars: m0=mean(b2), q0=mean(b2^2), mW[r]=mean(w2_r), q1[r]=mean(b2*w2_r),
//          Q2[r,r2]=mean(w2_r*w2_r2)   (all means over E*D=2048)
// ---------------------------------------------------------------------------
__global__ __launch_bounds__(1024) void hr_pre(
    const float* __restrict__ ee, const float* __restrict__ gam,
    const float* __restrict__ bta, const float* __restrict__ w2,
    const float* __restrict__ b2, const float* __restrict__ wq,
    const float* __restrict__ wk, float* __restrict__ ws)
{
    __shared__ float sge[2048];
    __shared__ float sK[2048];
    __shared__ float sWqK[2048];
    __shared__ float sred[1024];
    __shared__ float sacc[32];
    const int tid = threadIdx.x;

    // ---- LayerNorm(expert_embedding) over all 2048 elems ----
    float e0 = ee[tid], e1 = ee[tid + 1024];
    sred[tid] = e0 + e1;
    __syncthreads();
    for (int s = 512; s > 0; s >>= 1) {
        if (tid < s) sred[tid] += sred[tid + s];
        __syncthreads();
    }
    const float mu = sred[0] * (1.f / 2048.f);
    __syncthreads();
    float d0 = e0 - mu, d1 = e1 - mu;
    sred[tid] = d0 * d0 + d1 * d1;
    __syncthreads();
    for (int s = 512; s > 0; s >>= 1) {
        if (tid < s) sred[tid] += sred[tid + s];
        __syncthreads();
    }
    const float rsq = rsqrtf(sred[0] * (1.f / 2048.f) + 1e-5f);
    sge[tid]        = d0 * rsq * gam[tid] + bta[tid];
    sge[tid + 1024] = d1 * rsq * gam[tid + 1024] + bta[tid + 1024];
    if (tid < 32) sacc[tid] = 0.f;
    __syncthreads();

    // ---- K[e2][a] ----
    {
        int o = tid;
        #pragma unroll
        for (int it = 0; it < 2; ++it, o += 1024) {
            int e2 = o >> 7, a = o & 127;
            const float* gg = sge + (e2 << 7);
            const float* wr = wk + (a << 7);
            float s = 0.f;
            #pragma unroll 8
            for (int d = 0; d < 128; ++d) s = fmaf(gg[d], wr[d], s);
            sK[o] = s;
        }
    }
    __syncthreads();

    // ---- WqK[e2][d] ----
    {
        int o = tid;
        #pragma unroll
        for (int it = 0; it < 2; ++it, o += 1024) {
            int e2 = o >> 7, d = o & 127;
            const float* kk = sK + (e2 << 7);
            float s = 0.f;
            #pragma unroll 8
            for (int a = 0; a < 128; ++a) s = fmaf(wq[(a << 7) + d], kk[a], s);
            sWqK[o] = s;
        }
    }
    __syncthreads();

    // ---- PKt[e2][r][e] ----
    if (tid < 1024) {
        int e2 = tid >> 6, r = (tid >> 4) & 3, e = tid & 15;
        const float* wqk = sWqK + (e2 << 7);
        float s = 0.f;
        #pragma unroll 4
        for (int d = 0; d < 128; ++d) {
            int ed = (e << 7) + d;
            s = fmaf(w2[ed * 4 + r] * gam[ed], wqk[d], s);
        }
        ws[WS_PKT + tid] = s;
    }

    // ---- D1K / GqK / BqK : [e2][e] ----
    if (tid < 256) {
        int e2 = tid >> 4, e = tid & 15;
        const float* wqk = sWqK + (e2 << 7);
        float s1 = 0.f, s2 = 0.f, s3 = 0.f;
        #pragma unroll 4
        for (int d = 0; d < 128; ++d) {
            int ed = (e << 7) + d;
            float w = wqk[d];
            float g = gam[ed];
            s1 = fmaf(b2[ed] * g, w, s1);
            s2 = fmaf(g, w, s2);
            s3 = fmaf(bta[ed], w, s3);
        }
        ws[WS_D1K + tid] = s1;
        ws[WS_GQK + tid] = s2;
        ws[WS_BQK + tid] = s3;
    }

    // ---- scalars (26 block-wide reductions in one pass) ----
    {
        float pa[26];
        #pragma unroll
        for (int j = 0; j < 26; ++j) pa[j] = 0.f;
        for (int i = tid; i < 2048; i += 1024) {
            float b = b2[i];
            float4 w4 = *(const float4*)(w2 + i * 4);
            float wr[4] = {w4.x, w4.y, w4.z, w4.w};
            pa[0] += b;
            pa[1] += b * b;
            #pragma unroll
            for (int r = 0; r < 4; ++r) {
                pa[2 + r] += wr[r];
                pa[6 + r] += b * wr[r];
                #pragma unroll
                for (int r2 = 0; r2 < 4; ++r2) pa[10 + r * 4 + r2] += wr[r] * wr[r2];
            }
        }
        #pragma unroll
        for (int j = 0; j < 26; ++j) {
            float v = pa[j];
            v += __shfl_xor(v, 32);
            v += __shfl_xor(v, 16);
            v += __shfl_xor(v, 8);
            v += __shfl_xor(v, 4);
            v += __shfl_xor(v, 2);
            v += __shfl_xor(v, 1);
            if ((tid & 63) == 0) atomicAdd(&sacc[j], v);
        }
    }
    __syncthreads();
    if (tid < 26) ws[WS_SCAL + tid] = sacc[tid] * (1.f / 2048.f);
}

// ---------------------------------------------------------------------------
// Main kernel: 1024 blocks x 256 threads. Each wave (64 lanes) handles 4
// tokens: 20 length-2048 dot products (coalesced float4 loads), butterfly
// reduce, then 16 threads per token do the tiny routing tail.
// ---------------------------------------------------------------------------
__global__ __launch_bounds__(256) void hr_main(
    const float* __restrict__ hidden, const float* __restrict__ wv,
    const float* __restrict__ wvb, const float* __restrict__ w1,
    const float* __restrict__ b1, const float* __restrict__ tab,
    float* __restrict__ out)
{
    __shared__ float tabs[1824];
    __shared__ float red[16][20];
    const int tid  = threadIdx.x;
    const int wave = tid >> 6;
    const int lane = tid & 63;

    // stage precomputed tables into LDS
    for (int i = tid; i < WS_TOT; i += 256) tabs[i] = tab[i];

    const int tok0 = (blockIdx.x << 4) + (wave << 2);
    const float* hb = hidden + (size_t)tok0 * INDIM + (lane << 2);

    float acc[NROWS][4];
    #pragma unroll
    for (int w = 0; w < NROWS; ++w) {
        acc[w][0] = 0.f; acc[w][1] = 0.f; acc[w][2] = 0.f; acc[w][3] = 0.f;
    }

    for (int c = 0; c < 8; ++c) {
        const int off = c << 8;
        float4 h0 = *(const float4*)(hb + off);
        float4 h1 = *(const float4*)(hb + off + INDIM);
        float4 h2 = *(const float4*)(hb + off + 2 * INDIM);
        float4 h3 = *(const float4*)(hb + off + 3 * INDIM);
        #pragma unroll
        for (int w = 0; w < NROWS; ++w) {
            const float* wr = (w < 16) ? (wv + (w << 11)) : (w1 + ((w - 16) << 11));
            float4 wf = *(const float4*)(wr + off + (lane << 2));
            acc[w][0] = fmaf(h0.x, wf.x, fmaf(h0.y, wf.y, fmaf(h0.z, wf.z, fmaf(h0.w, wf.w, acc[w][0]))));
            acc[w][1] = fmaf(h1.x, wf.x, fmaf(h1.y, wf.y, fmaf(h1.z, wf.z, fmaf(h1.w, wf.w, acc[w][1]))));
            acc[w][2] = fmaf(h2.x, wf.x, fmaf(h2.y, wf.y, fmaf(h2.z, wf.z, fmaf(h2.w, wf.w, acc[w][2]))));
            acc[w][3] = fmaf(h3.x, wf.x, fmaf(h3.y, wf.y, fmaf(h3.z, wf.z, fmaf(h3.w, wf.w, acc[w][3]))));
        }
    }

    // full-wave butterfly reduce each of the 80 accumulators
    #pragma unroll
    for (int w = 0; w < NROWS; ++w) {
        #pragma unroll
        for (int t = 0; t < 4; ++t) {
            float v = acc[w][t];
            v += __shfl_xor(v, 32);
            v += __shfl_xor(v, 16);
            v += __shfl_xor(v, 8);
            v += __shfl_xor(v, 4);
            v += __shfl_xor(v, 2);
            v += __shfl_xor(v, 1);
            acc[w][t] = v;   // all lanes hold the sum
        }
    }
    if (lane < 4) {
        const int row = (wave << 2) + lane;
        #pragma unroll
        for (int w = 0; w < NROWS; ++w) {
            float v = (lane == 0) ? acc[w][0]
                    : (lane == 1) ? acc[w][1]
                    : (lane == 2) ? acc[w][2] : acc[w][3];
            red[row][w] = v;
        }
    }
    __syncthreads();

    // ---- tail: 16 threads per token, thread = (tok, e) ----
    const int tok = tid >> 4;
    const int e   = tid & 15;

    float ig[16];
    #pragma unroll
    for (int j = 0; j < 16; ++j) ig[j] = red[tok][j] + wvb[j];
    float h[4];
    #pragma unroll
    for (int r = 0; r < 4; ++r) h[r] = fmaxf(red[tok][16 + r] + b1[r], 0.f);

    // LN stats of dyn (quadratic in h)
    float muT = tabs[WS_SCAL + 0];
    float e2m = tabs[WS_SCAL + 1];
    #pragma unroll
    for (int r = 0; r < 4; ++r) {
        muT = fmaf(h[r], tabs[WS_SCAL + 2 + r], muT);
        e2m = fmaf(2.f * h[r], tabs[WS_SCAL + 6 + r], e2m);
        #pragma unroll
        for (int r2 = 0; r2 < 4; ++r2)
            e2m = fmaf(h[r] * h[r2], tabs[WS_SCAL + 10 + r * 4 + r2], e2m);
    }
    const float var = e2m - muT * muT;
    const float rsq = rsqrtf(var + 1e-5f);

    // scores s[e][e2], softmax over e2, gate[e] = sim·ig
    float sv[16];
    #pragma unroll
    for (int e2 = 0; e2 < 16; ++e2) {
        float s = tabs[WS_D1K + (e2 << 4) + e];
        s = fmaf(h[0], tabs[(e2 << 6) + e], s);
        s = fmaf(h[1], tabs[(e2 << 6) + 16 + e], s);
        s = fmaf(h[2], tabs[(e2 << 6) + 32 + e], s);
        s = fmaf(h[3], tabs[(e2 << 6) + 48 + e], s);
        s = fmaf(-muT, tabs[WS_GQK + (e2 << 4) + e], s);
        sv[e2] = (rsq * s + tabs[WS_BQK + (e2 << 4) + e]) * SIM_SCALE;
    }
    float mx = sv[0];
    #pragma unroll
    for (int e2 = 1; e2 < 16; ++e2) mx = fmaxf(mx, sv[e2]);
    float den = 0.f, gate = 0.f;
    #pragma unroll
    for (int e2 = 0; e2 < 16; ++e2) {
        float p = __expf(sv[e2] - mx);
        den += p;
        gate = fmaf(p, ig[e2], gate);
    }
    gate /= den;

    // rw = softmax(gate) across the 16 lanes of this token group
    float gm = gate;
    gm = fmaxf(gm, __shfl_xor(gm, 1));
    gm = fmaxf(gm, __shfl_xor(gm, 2));
    gm = fmaxf(gm, __shfl_xor(gm, 4));
    gm = fmaxf(gm, __shfl_xor(gm, 8));
    float ex = __expf(gate - gm);
    float es = ex;
    es += __shfl_xor(es, 1);
    es += __shfl_xor(es, 2);
    es += __shfl_xor(es, 4);
    es += __shfl_xor(es, 8);
    const float rw = ex / es;

    // top-2 (ties -> lower index, matching jax.lax.top_k)
    float v1 = rw; int i1 = e;
    #pragma unroll
    for (int m = 1; m <= 8; m <<= 1) {
        float ov = __shfl_xor(v1, m);
        int   oi = __shfl_xor(i1, m);
        if (ov > v1 || (ov == v1 && oi < i1)) { v1 = ov; i1 = oi; }
    }
    float v2 = (e == i1) ? -INFINITY : rw; int i2 = e;
    #pragma unroll
    for (int m = 1; m <= 8; m <<= 1) {
        float ov = __shfl_xor(v2, m);
        int   oi = __shfl_xor(i2, m);
        if (ov > v2 || (ov == v2 && oi < i2)) { v2 = ov; i2 = oi; }
    }

    // sharpened softmax over the two kept entries; others exactly 0
    float oval = 0.f;
    if (e == i1 || e == i2) {
        float t = __expf((v2 - v1) * 10.f);
        oval = (e == i1) ? (1.f / (1.f + t)) : (t / (1.f + t));
    }
    out[(((size_t)blockIdx.x << 4) + tok) * 16 + e] = oval;
}

// ---------------------------------------------------------------------------
extern "C" void kernel_launch(void* const* d_in, const int* in_sizes, int n_in,
                              void* d_out, int out_size, void* d_ws, size_t ws_size,
                              hipStream_t stream)
{
    const float* hidden = (const float*)d_in[0];   // (4,4096,2048)
    const float* ee     = (const float*)d_in[1];   // (16,128)
    const float* gam    = (const float*)d_in[2];   // (16,128)
    const float* bta    = (const float*)d_in[3];   // (16,128)
    const float* wv     = (const float*)d_in[4];   // (16,2048)
    const float* wvb    = (const float*)d_in[5];   // (16,)
    const float* w1     = (const float*)d_in[6];   // (4,2048)
    const float* b1     = (const float*)d_in[7];   // (4,)
    const float* w2     = (const float*)d_in[8];   // (2048,4)
    const float* b2     = (const float*)d_in[9];   // (2048,)
    const float* wq     = (const float*)d_in[10];  // (128,128)
    const float* wk     = (const float*)d_in[11];  // (128,128)
    // d_in[12] = top_k (fixed at 2)
    float* out = (float*)d_out;
    float* ws  = (float*)d_ws;

    hipLaunchKernelGGL(hr_pre, dim3(1), dim3(1024), 0, stream,
                       ee, gam, bta, w2, b2, wq, wk, ws);
    hipLaunchKernelGGL(hr_main, dim3(NTOK / 16), dim3(256), 0, stream,
                       hidden, wv, wvb, w1, b1, ws, out);
}

// Round 2
// 267.692 us; speedup vs baseline: 1.4094x; 1.4094x over previous
//
#include <hip/hip_runtime.h>
#include <math.h>

// Problem constants (from reference): B=4,S=4096,IN=2048,E=16,D=128,A=128,R=4
#define NTOK   16384   // B*S
#define INDIM  2048
#define NEXP   16
#define DDIM   128
#define NROWS  20      // 16 Wv rows + 4 mlp_w1 rows

// workspace (float) layout
#define WS_PKT  0      // PKt[e2][r][e]  : 16*4*16 = 1024
#define WS_D1K  1024   // [e2][e] 256
#define WS_GQK  1280   // [e2][e] 256
#define WS_BQK  1536   // [e2][e] 256
#define WS_SCAL 1792   // m0,q0,mW[4],q1[4],Q2[16] = 26
#define WS_TOT  1818

#define SIM_SCALE 0.08838834764831845f  // 1/sqrt(128)

// ---------------------------------------------------------------------------
// Precompute kernel v2: 17 blocks x 256 threads.
//   blocks 0..15 (one per e2): redundant in-block LN(ee) -> ge row e2,
//     K[e2,a] = ge[e2,:]·Wk[a,:]        (2 threads per a, shfl combine)
//     WqK[e2,d] = sum_a Wq[a,d]*K[e2,a] (2 threads per d)
//     PKt[e2,r,e], D1K/GqK/BqK[e2,e]    (4 threads per output)
//   block 16: the 26 scalar means over E*D=2048.
// All global writes go to disjoint ws regions; single launch, fully parallel.
// ---------------------------------------------------------------------------
__global__ __launch_bounds__(256) void hr_pre2(
    const float* __restrict__ ee, const float* __restrict__ gam,
    const float* __restrict__ bta, const float* __restrict__ w2,
    const float* __restrict__ b2, const float* __restrict__ wq,
    const float* __restrict__ wk, float* __restrict__ ws)
{
    const int tid  = threadIdx.x;
    const int bx   = blockIdx.x;
    const int lane = tid & 63;
    const int wave = tid >> 6;

    if (bx == 16) {
        // ---- 26 scalar reductions over i=0..2047 ----
        __shared__ float sacc[26];
        if (tid < 26) sacc[tid] = 0.f;
        __syncthreads();
        float pa[26];
        #pragma unroll
        for (int j = 0; j < 26; ++j) pa[j] = 0.f;
        for (int i = tid; i < 2048; i += 256) {
            float b = b2[i];
            float4 w4 = *(const float4*)(w2 + i * 4);
            float wr[4] = {w4.x, w4.y, w4.z, w4.w};
            pa[0] += b;
            pa[1] += b * b;
            #pragma unroll
            for (int r = 0; r < 4; ++r) {
                pa[2 + r] += wr[r];
                pa[6 + r] += b * wr[r];
                #pragma unroll
                for (int r2 = 0; r2 < 4; ++r2) pa[10 + r * 4 + r2] += wr[r] * wr[r2];
            }
        }
        #pragma unroll
        for (int j = 0; j < 26; ++j) {
            float v = pa[j];
            v += __shfl_xor(v, 32);
            v += __shfl_xor(v, 16);
            v += __shfl_xor(v, 8);
            v += __shfl_xor(v, 4);
            v += __shfl_xor(v, 2);
            v += __shfl_xor(v, 1);
            if (lane == 0) atomicAdd(&sacc[j], v);
        }
        __syncthreads();
        if (tid < 26) ws[WS_SCAL + tid] = sacc[tid] * (1.f / 2048.f);
        return;
    }

    const int e2 = bx;
    __shared__ float sge[128];    // ge row for this e2
    __shared__ float sK[128];     // K[e2][a]
    __shared__ float sWqK[128];   // WqK[e2][d]
    __shared__ float sred[8];

    // ---- LN stats over all 2048 elems of ee (redundant per block) ----
    float v8[8];
    float s = 0.f;
    #pragma unroll
    for (int j = 0; j < 8; ++j) {
        v8[j] = ee[tid + j * 256];
        s += v8[j];
    }
    s += __shfl_xor(s, 32); s += __shfl_xor(s, 16); s += __shfl_xor(s, 8);
    s += __shfl_xor(s, 4);  s += __shfl_xor(s, 2);  s += __shfl_xor(s, 1);
    if (lane == 0) sred[wave] = s;
    __syncthreads();
    const float mu = (sred[0] + sred[1] + sred[2] + sred[3]) * (1.f / 2048.f);
    float q = 0.f;
    #pragma unroll
    for (int j = 0; j < 8; ++j) {
        float d = v8[j] - mu;
        q += d * d;
    }
    q += __shfl_xor(q, 32); q += __shfl_xor(q, 16); q += __shfl_xor(q, 8);
    q += __shfl_xor(q, 4);  q += __shfl_xor(q, 2);  q += __shfl_xor(q, 1);
    if (lane == 0) sred[4 + wave] = q;
    __syncthreads();
    const float rsq = rsqrtf((sred[4] + sred[5] + sred[6] + sred[7]) * (1.f / 2048.f) + 1e-5f);

    // ---- ge row e2 into LDS ----
    if (tid < 128) {
        int idx = (e2 << 7) + tid;
        sge[tid] = (ee[idx] - mu) * rsq * gam[idx] + bta[idx];
    }
    __syncthreads();

    // ---- K[e2][a], 2 threads per a ----
    {
        int a = tid >> 1, half = tid & 1;
        const float* wr = wk + (a << 7) + (half << 6);
        const float* gg = sge + (half << 6);
        float acc = 0.f;
        #pragma unroll 8
        for (int j = 0; j < 64; ++j) acc = fmaf(gg[j], wr[j], acc);
        acc += __shfl_xor(acc, 1);
        if (half == 0) sK[a] = acc;
    }
    __syncthreads();

    // ---- WqK[e2][d], 2 threads per d ----
    {
        int d = tid >> 1, half = tid & 1;
        float acc = 0.f;
        #pragma unroll 8
        for (int j = 0; j < 64; ++j) {
            int a = (half << 6) + j;
            acc = fmaf(wq[(a << 7) + d], sK[a], acc);
        }
        acc += __shfl_xor(acc, 1);
        if (half == 0) sWqK[d] = acc;
    }
    __syncthreads();

    // ---- PKt[e2][r][e], 4 threads per output ----
    {
        int o = tid >> 2, qd = tid & 3;
        int r = o >> 4, e = o & 15;
        float acc = 0.f;
        #pragma unroll 8
        for (int j = 0; j < 32; ++j) {
            int d  = (qd << 5) + j;
            int ed = (e << 7) + d;
            acc = fmaf(w2[ed * 4 + r] * gam[ed], sWqK[d], acc);
        }
        acc += __shfl_xor(acc, 1);
        acc += __shfl_xor(acc, 2);
        if (qd == 0) ws[WS_PKT + (e2 << 6) + (r << 4) + e] = acc;
    }

    // ---- D1K / GqK / BqK [e2][e], 4 threads per output, 3 kinds ----
    if (tid < 192) {
        int kind = tid >> 6;            // 0=D1K 1=GqK 2=BqK
        int e    = (tid >> 2) & 15;
        int qd   = tid & 3;
        float acc = 0.f;
        #pragma unroll 8
        for (int j = 0; j < 32; ++j) {
            int d  = (qd << 5) + j;
            int ed = (e << 7) + d;
            float w = sWqK[d];
            float t = (kind == 0) ? b2[ed] * gam[ed]
                    : (kind == 1) ? gam[ed]
                                  : bta[ed];
            acc = fmaf(t, w, acc);
        }
        acc += __shfl_xor(acc, 1);
        acc += __shfl_xor(acc, 2);
        if (qd == 0) ws[WS_D1K + (kind << 8) + (e2 << 4) + e] = acc;
    }
}

// ---------------------------------------------------------------------------
// Main kernel: 1024 blocks x 256 threads. Each wave (64 lanes) handles 4
// tokens: 20 length-2048 dot products (coalesced float4 loads), butterfly
// reduce, then 16 threads per token do the tiny routing tail.
// ---------------------------------------------------------------------------
__global__ __launch_bounds__(256) void hr_main(
    const float* __restrict__ hidden, const float* __restrict__ wv,
    const float* __restrict__ wvb, const float* __restrict__ w1,
    const float* __restrict__ b1, const float* __restrict__ tab,
    float* __restrict__ out)
{
    __shared__ float tabs[1824];
    __shared__ float red[16][20];
    const int tid  = threadIdx.x;
    const int wave = tid >> 6;
    const int lane = tid & 63;

    // stage precomputed tables into LDS
    for (int i = tid; i < WS_TOT; i += 256) tabs[i] = tab[i];

    const int tok0 = (blockIdx.x << 4) + (wave << 2);
    const float* hb = hidden + (size_t)tok0 * INDIM + (lane << 2);

    float acc[NROWS][4];
    #pragma unroll
    for (int w = 0; w < NROWS; ++w) {
        acc[w][0] = 0.f; acc[w][1] = 0.f; acc[w][2] = 0.f; acc[w][3] = 0.f;
    }

    for (int c = 0; c < 8; ++c) {
        const int off = c << 8;
        float4 h0 = *(const float4*)(hb + off);
        float4 h1 = *(const float4*)(hb + off + INDIM);
        float4 h2 = *(const float4*)(hb + off + 2 * INDIM);
        float4 h3 = *(const float4*)(hb + off + 3 * INDIM);
        #pragma unroll
        for (int w = 0; w < NROWS; ++w) {
            const float* wr = (w < 16) ? (wv + (w << 11)) : (w1 + ((w - 16) << 11));
            float4 wf = *(const float4*)(wr + off + (lane << 2));
            acc[w][0] = fmaf(h0.x, wf.x, fmaf(h0.y, wf.y, fmaf(h0.z, wf.z, fmaf(h0.w, wf.w, acc[w][0]))));
            acc[w][1] = fmaf(h1.x, wf.x, fmaf(h1.y, wf.y, fmaf(h1.z, wf.z, fmaf(h1.w, wf.w, acc[w][1]))));
            acc[w][2] = fmaf(h2.x, wf.x, fmaf(h2.y, wf.y, fmaf(h2.z, wf.z, fmaf(h2.w, wf.w, acc[w][2]))));
            acc[w][3] = fmaf(h3.x, wf.x, fmaf(h3.y, wf.y, fmaf(h3.z, wf.z, fmaf(h3.w, wf.w, acc[w][3]))));
        }
    }

    // full-wave butterfly reduce each of the 80 accumulators
    #pragma unroll
    for (int w = 0; w < NROWS; ++w) {
        #pragma unroll
        for (int t = 0; t < 4; ++t) {
            float v = acc[w][t];
            v += __shfl_xor(v, 32);
            v += __shfl_xor(v, 16);
            v += __shfl_xor(v, 8);
            v += __shfl_xor(v, 4);
            v += __shfl_xor(v, 2);
            v += __shfl_xor(v, 1);
            acc[w][t] = v;   // all lanes hold the sum
        }
    }
    if (lane < 4) {
        const int row = (wave << 2) + lane;
        #pragma unroll
        for (int w = 0; w < NROWS; ++w) {
            float v = (lane == 0) ? acc[w][0]
                    : (lane == 1) ? acc[w][1]
                    : (lane == 2) ? acc[w][2] : acc[w][3];
            red[row][w] = v;
        }
    }
    __syncthreads();

    // ---- tail: 16 threads per token, thread = (tok, e) ----
    const int tok = tid >> 4;
    const int e   = tid & 15;

    float ig[16];
    #pragma unroll
    for (int j = 0; j < 16; ++j) ig[j] = red[tok][j] + wvb[j];
    float h[4];
    #pragma unroll
    for (int r = 0; r < 4; ++r) h[r] = fmaxf(red[tok][16 + r] + b1[r], 0.f);

    // LN stats of dyn (quadratic in h)
    float muT = tabs[WS_SCAL + 0];
    float e2m = tabs[WS_SCAL + 1];
    #pragma unroll
    for (int r = 0; r < 4; ++r) {
        muT = fmaf(h[r], tabs[WS_SCAL + 2 + r], muT);
        e2m = fmaf(2.f * h[r], tabs[WS_SCAL + 6 + r], e2m);
        #pragma unroll
        for (int r2 = 0; r2 < 4; ++r2)
            e2m = fmaf(h[r] * h[r2], tabs[WS_SCAL + 10 + r * 4 + r2], e2m);
    }
    const float var = e2m - muT * muT;
    const float rsq = rsqrtf(var + 1e-5f);

    // scores s[e][e2], softmax over e2, gate[e] = sim·ig
    float sv[16];
    #pragma unroll
    for (int e2 = 0; e2 < 16; ++e2) {
        float s = tabs[WS_D1K + (e2 << 4) + e];
        s = fmaf(h[0], tabs[(e2 << 6) + e], s);
        s = fmaf(h[1], tabs[(e2 << 6) + 16 + e], s);
        s = fmaf(h[2], tabs[(e2 << 6) + 32 + e], s);
        s = fmaf(h[3], tabs[(e2 << 6) + 48 + e], s);
        s = fmaf(-muT, tabs[WS_GQK + (e2 << 4) + e], s);
        sv[e2] = (rsq * s + tabs[WS_BQK + (e2 << 4) + e]) * SIM_SCALE;
    }
    float mx = sv[0];
    #pragma unroll
    for (int e2 = 1; e2 < 16; ++e2) mx = fmaxf(mx, sv[e2]);
    float den = 0.f, gate = 0.f;
    #pragma unroll
    for (int e2 = 0; e2 < 16; ++e2) {
        float p = __expf(sv[e2] - mx);
        den += p;
        gate = fmaf(p, ig[e2], gate);
    }
    gate /= den;

    // rw = softmax(gate) across the 16 lanes of this token group
    float gm = gate;
    gm = fmaxf(gm, __shfl_xor(gm, 1));
    gm = fmaxf(gm, __shfl_xor(gm, 2));
    gm = fmaxf(gm, __shfl_xor(gm, 4));
    gm = fmaxf(gm, __shfl_xor(gm, 8));
    float ex = __expf(gate - gm);
    float es = ex;
    es += __shfl_xor(es, 1);
    es += __shfl_xor(es, 2);
    es += __shfl_xor(es, 4);
    es += __shfl_xor(es, 8);
    const float rw = ex / es;

    // top-2 (ties -> lower index, matching jax.lax.top_k)
    float v1 = rw; int i1 = e;
    #pragma unroll
    for (int m = 1; m <= 8; m <<= 1) {
        float ov = __shfl_xor(v1, m);
        int   oi = __shfl_xor(i1, m);
        if (ov > v1 || (ov == v1 && oi < i1)) { v1 = ov; i1 = oi; }
    }
    float v2 = (e == i1) ? -INFINITY : rw; int i2 = e;
    #pragma unroll
    for (int m = 1; m <= 8; m <<= 1) {
        float ov = __shfl_xor(v2, m);
        int   oi = __shfl_xor(i2, m);
        if (ov > v2 || (ov == v2 && oi < i2)) { v2 = ov; i2 = oi; }
    }

    // sharpened softmax over the two kept entries; others exactly 0
    float oval = 0.f;
    if (e == i1 || e == i2) {
        float t = __expf((v2 - v1) * 10.f);
        oval = (e == i1) ? (1.f / (1.f + t)) : (t / (1.f + t));
    }
    out[(((size_t)blockIdx.x << 4) + tok) * 16 + e] = oval;
}

// ---------------------------------------------------------------------------
extern "C" void kernel_launch(void* const* d_in, const int* in_sizes, int n_in,
                              void* d_out, int out_size, void* d_ws, size_t ws_size,
                              hipStream_t stream)
{
    const float* hidden = (const float*)d_in[0];   // (4,4096,2048)
    const float* ee     = (const float*)d_in[1];   // (16,128)
    const float* gam    = (const float*)d_in[2];   // (16,128)
    const float* bta    = (const float*)d_in[3];   // (16,128)
    const float* wv     = (const float*)d_in[4];   // (16,2048)
    const float* wvb    = (const float*)d_in[5];   // (16,)
    const float* w1     = (const float*)d_in[6];   // (4,2048)
    const float* b1     = (const float*)d_in[7];   // (4,)
    const float* w2     = (const float*)d_in[8];   // (2048,4)
    const float* b2     = (const float*)d_in[9];   // (2048,)
    const float* wq     = (const float*)d_in[10];  // (128,128)
    const float* wk     = (const float*)d_in[11];  // (128,128)
    // d_in[12] = top_k (fixed at 2)
    float* out = (float*)d_out;
    float* ws  = (float*)d_ws;

    hipLaunchKernelGGL(hr_pre2, dim3(17), dim3(256), 0, stream,
                       ee, gam, bta, w2, b2, wq, wk, ws);
    hipLaunchKernelGGL(hr_main, dim3(NTOK / 16), dim3(256), 0, stream,
                       hidden, wv, wvb, w1, b1, ws, out);
}